// Round 11
// baseline (2636.412 us; speedup 1.0000x reference)
//
#include <hip/hip_runtime.h>

#define N_NODES 100000
#define N_EDGES 1600000
#define DIM     128
#define NGRAPH  64
#define NCLS    10
#define ZROW    N_NODES   // zeroed pad row id in feature buffers

#define NBLK    64                  // histogram/scatter blocks
#define EPB     (N_EDGES / NBLK)    // 25000 edges per block (exact)
#define RANGE   50000               // node ids per src-histogram pass (2 passes)
#define BNODE   64                  // nodes per dst bucket
#define NBKT    1563                // ceil(N_NODES / BNODE)

typedef __bf16 bf16x8 __attribute__((ext_vector_type(8)));
typedef float  f32x4  __attribute__((ext_vector_type(4)));

// ---- bf16 pack/unpack helpers (manual RNE) ----------------------------------
__device__ __forceinline__ ushort f2bf(float x) {
  uint b = __float_as_uint(x);
  b += 0x7fffu + ((b >> 16) & 1u);
  return (ushort)(b >> 16);
}
__device__ __forceinline__ uint pack2(float lo, float hi) {
  return (uint)f2bf(lo) | ((uint)f2bf(hi) << 16);
}
__device__ __forceinline__ float unlo(uint u) { return __uint_as_float(u << 16); }
__device__ __forceinline__ float unhi(uint u) { return __uint_as_float(u & 0xffff0000u); }

// ---------------- init: zero pool, cnt, both pad rows, bucket totals ---------
__global__ void k_init(float* __restrict__ pool, float* __restrict__ cnt,
                       uint* __restrict__ pad1, uint* __restrict__ pad2,
                       int* __restrict__ btot) {
  int t = threadIdx.x;
  for (int i = t; i < NGRAPH * DIM; i += 256) pool[i] = 0.f;
  if (t < NGRAPH) cnt[t] = 0.f;
  if (t < DIM / 2) { pad1[t] = 0u; pad2[t] = 0u; }
  for (int i = t; i < NBKT; i += 256) btot[i] = 0;
}

// ---------------- src-degree histograms (2 ranges, LDS-privatized) -----------
__global__ __launch_bounds__(256)
void k_hist(const int* __restrict__ src, ushort* __restrict__ part) {
  extern __shared__ uint cnt_[];   // RANGE/2 words = 100 KB
  int p = blockIdx.y;              // src range 0/1
  int b = blockIdx.x;
  int base = p * RANGE;
  for (int i = threadIdx.x; i < RANGE / 2; i += 256) cnt_[i] = 0;
  __syncthreads();
  int cb = b * EPB;
  for (int j = threadIdx.x; j < EPB; j += 256) {
    int v = src[cb + j] - base;
    if ((unsigned)v < RANGE) atomicAdd(&cnt_[v >> 1], 1u << ((v & 1) * 16));
  }
  __syncthreads();
  uint* o = (uint*)(part + ((size_t)p * NBLK + b) * RANGE);
  for (int i = threadIdx.x; i < RANGE / 2; i += 256) o[i] = cnt_[i];
}

// ---------------- sum partials -> deg_out ------------------------------------
__global__ void k_degout(const ushort* __restrict__ part, int* __restrict__ deg_out) {
  int n = blockIdx.x * 256 + threadIdx.x;
  if (n >= N_NODES) return;
  int r = n / RANGE, i = n % RANGE;
  const ushort* p0 = part + ((size_t)r * NBLK) * RANGE + i;
  int s = 0;
  for (int b = 0; b < NBLK; ++b) s += p0[(size_t)b * RANGE];
  deg_out[n] = s;
}

// ---------------- dst bucket histogram ---------------------------------------
__global__ __launch_bounds__(256)
void k_bhist(const int* __restrict__ dst, int* __restrict__ btot) {
  __shared__ uint h[NBKT];
  for (int i = threadIdx.x; i < NBKT; i += 256) h[i] = 0;
  __syncthreads();
  int cb = blockIdx.x * EPB;
  for (int j = threadIdx.x; j < EPB; j += 256)
    atomicAdd(&h[dst[cb + j] >> 6], 1u);
  __syncthreads();
  for (int i = threadIdx.x; i < NBKT; i += 256)
    if (h[i]) atomicAdd(&btot[i], (int)h[i]);
}

// ---------------- bucket scan: btot -> bbase (exclusive) + cursor ------------
__global__ void k_bscan(const int* __restrict__ btot, int* __restrict__ bbase,
                        int* __restrict__ bcur) {
  __shared__ int tot[256];
  int t = threadIdx.x;     // 256 threads x 7 buckets each (1792 >= 1564)
  int c[7]; int s = 0;
  #pragma unroll
  for (int i = 0; i < 7; ++i) {
    int gi = t * 7 + i;
    c[i] = (gi < NBKT) ? btot[gi] : 0;
    s += c[i];
  }
  tot[t] = s;
  __syncthreads();
  for (int off = 1; off < 256; off <<= 1) {
    int x = (t >= off) ? tot[t - off] : 0;
    __syncthreads();
    tot[t] += x;
    __syncthreads();
  }
  int run = tot[t] - s;    // exclusive offset of this thread's chunk
  #pragma unroll
  for (int i = 0; i < 7; ++i) {
    int gi = t * 7 + i;
    if (gi <= NBKT) {
      bbase[gi] = run;
      if (gi < NBKT) bcur[gi] = run;
    }
    run += c[i];
  }
}

// ---------------- scatter edges into dst buckets (unordered within bucket) ---
__global__ __launch_bounds__(256)
void k_scatter(const int* __restrict__ src, const int* __restrict__ dst,
               int* __restrict__ bcur, uint* __restrict__ blist) {
  __shared__ uint h[NBKT];
  __shared__ uint st[NBKT];
  for (int i = threadIdx.x; i < NBKT; i += 256) h[i] = 0;
  __syncthreads();
  int cb = blockIdx.x * EPB;
  for (int j = threadIdx.x; j < EPB; j += 256)
    atomicAdd(&h[dst[cb + j] >> 6], 1u);
  __syncthreads();
  for (int i = threadIdx.x; i < NBKT; i += 256) {
    st[i] = (uint)atomicAdd(&bcur[i], (int)h[i]);
    h[i] = 0;   // reuse as local cursor
  }
  __syncthreads();
  for (int j = threadIdx.x; j < EPB; j += 256) {
    int d = dst[cb + j];
    int s = src[cb + j];
    int bk = d >> 6;
    uint pos = st[bk] + atomicAdd(&h[bk], 1u);
    blist[pos] = (uint)s | ((uint)(d & 63) << 17);   // src<2^17, dl 6 bits
  }
}

// ---------------- W -> bf16 transposed (B^T layout: Wt[c][k]) ----------------
__global__ void k_convW(const float* __restrict__ W1, const float* __restrict__ W2,
                        ushort* __restrict__ Wt1, ushort* __restrict__ Wt2) {
  int idx = blockIdx.x * 256 + threadIdx.x;
  const float* W = (idx < 16384) ? W1 : W2;
  ushort* Wt = (idx < 16384) ? Wt1 : Wt2;
  int t = idx & 16383;
  int c = t >> 7, k = t & 127;
  Wt[c * 128 + k] = f2bf(W[k * 128 + c]);
}

// ---------------- prescale: hs = bf16(h * rsqrt(deg_out[row])) ---------------
__global__ void k_prescale(const float4* __restrict__ h4, const int* __restrict__ deg_out,
                           uint4* __restrict__ out4) {
  int idx = blockIdx.x * blockDim.x + threadIdx.x;
  if (idx < N_NODES * 16) {
    int row = idx >> 4;
    int d = deg_out[row];
    float s = d > 0 ? rsqrtf((float)d) : 0.f;
    float4 v0 = h4[idx * 2];
    float4 v1 = h4[idx * 2 + 1];
    uint4 o;
    o.x = pack2(v0.x * s, v0.y * s);
    o.y = pack2(v0.z * s, v0.w * s);
    o.z = pack2(v1.x * s, v1.y * s);
    o.w = pack2(v1.z * s, v1.w * s);
    out4[idx] = o;
  }
}

// ---------------- fused bucket-aggregate + MFMA GEMM -------------------------
// One block per 64-node dst bucket (512 thr = 8 waves = 32 x 16-lane groups).
// Phase 1: groups stream the bucket's unordered edge list (8 edges/round,
//   8 independent 16B row loads in flight per lane), accumulating into LDS
//   f32 via native ds_add_f32; deg_in counted in LDS. Tail edges read the
//   zeroed pad row (value-safe).
// Phase 2: normalize by rsqrt(deg_in), pack bf16 into As.
// Phase 3: MFMA 64x128 @ 128x128 (proven fragment mapping), epilogue
//   bias+relu[+next-layer src norm], guarded bf16 store.
__global__ __launch_bounds__(512)
void k_agg(const uint* __restrict__ hs, const uint* __restrict__ blist,
           const int* __restrict__ bbase, const ushort* __restrict__ Wt,
           const float* __restrict__ bias, const int* __restrict__ deg_scale,
           ushort* __restrict__ out) {
  __shared__ float accum[BNODE][DIM + 1];   // 64 x 129 f32 = 33 KB
  __shared__ int dcnt[BNODE];
  __shared__ ushort As[BNODE][DIM + 8];     // 64 x 136 bf16 = 17.4 KB
  int tid = threadIdx.x;
  int bk = blockIdx.x;
  int n0 = bk << 6;

  for (int v = tid; v < BNODE * (DIM + 1); v += 512) ((float*)accum)[v] = 0.f;
  if (tid < BNODE) dcnt[tid] = 0;
  __syncthreads();

  int beg = bbase[bk], end = bbase[bk + 1];
  int lane = tid & 63, wv = tid >> 6;
  int gidx = tid >> 4, li = tid & 15;
  int glane = (gidx & 3) * 16;              // group's lane base within wave

  for (int rb = beg + gidx * 8; rb < end; rb += 256) {
    uint e = 0u;
    bool inr = (li < 8) && (rb + li < end);
    if (inr) e = blist[rb + li];
    if (inr) atomicAdd(&dcnt[e >> 17], 1);  // deg_in count (per edge, once)

    int srck[8], dlk[8];
    #pragma unroll
    for (int k = 0; k < 8; ++k) {
      uint ek = __shfl(e, glane + k);
      bool sel = (rb + k < end);
      srck[k] = sel ? (int)(ek & 0x1FFFFu) : ZROW;
      dlk[k]  = (int)(ek >> 17);
    }
    uint4 u[8];
    #pragma unroll
    for (int k = 0; k < 8; ++k)
      u[k] = *(const uint4*)(hs + (size_t)srck[k] * 64 + li * 4);
    #pragma unroll
    for (int k = 0; k < 8; ++k) {
      float* ap = &accum[dlk[k]][li * 8];
      atomicAdd(ap + 0, unlo(u[k].x)); atomicAdd(ap + 1, unhi(u[k].x));
      atomicAdd(ap + 2, unlo(u[k].y)); atomicAdd(ap + 3, unhi(u[k].y));
      atomicAdd(ap + 4, unlo(u[k].z)); atomicAdd(ap + 5, unhi(u[k].z));
      atomicAdd(ap + 6, unlo(u[k].w)); atomicAdd(ap + 7, unhi(u[k].w));
    }
  }
  __syncthreads();

  // normalize + pack bf16 (all 64 rows; deg==0 -> zeros)
  for (int v = tid; v < BNODE * (DIM / 2); v += 512) {
    int r = v >> 6, cp = v & 63;
    int dg = dcnt[r];
    float sc = dg > 0 ? rsqrtf((float)dg) : 0.f;
    ((uint*)&As[r][0])[cp] = pack2(accum[r][cp * 2] * sc, accum[r][cp * 2 + 1] * sc);
  }
  __syncthreads();

  // MFMA: wave w -> rows (w&3)*16..+15, cols (w>>2)*64..+63
  int lr = lane & 15, lk = lane >> 4;
  int strip = wv & 3, ch = wv >> 2;
  bf16x8 bfrag[4][4];
  #pragma unroll
  for (int ks = 0; ks < 4; ++ks)
    #pragma unroll
    for (int c2 = 0; c2 < 4; ++c2)
      bfrag[ks][c2] = *(const bf16x8*)(Wt + (size_t)(ch * 64 + c2 * 16 + lr) * 128 +
                                       ks * 32 + lk * 8);
  f32x4 acc[4] = {};
  #pragma unroll
  for (int ks = 0; ks < 4; ++ks) {
    bf16x8 af = *(const bf16x8*)&As[strip * 16 + lr][ks * 32 + lk * 8];
    #pragma unroll
    for (int c2 = 0; c2 < 4; ++c2)
      acc[c2] = __builtin_amdgcn_mfma_f32_16x16x32_bf16(af, bfrag[ks][c2], acc[c2], 0, 0, 0);
  }

  #pragma unroll
  for (int rr = 0; rr < 4; ++rr) {
    int row = n0 + strip * 16 + lk * 4 + rr;
    if (row >= N_NODES) continue;
    float s = 1.f;
    if (deg_scale) {
      int d = deg_scale[row];
      s = d > 0 ? rsqrtf((float)d) : 0.f;
    }
    #pragma unroll
    for (int c2 = 0; c2 < 4; ++c2) {
      int col = ch * 64 + c2 * 16 + lr;
      float v = fmaxf(acc[c2][rr] + bias[col], 0.f) * s;
      out[(size_t)row * 128 + col] = f2bf(v);
    }
  }
}

// ---------------- segmented mean-pool: 64 rows per wave ----------------------
__global__ __launch_bounds__(256)
void k_pool(const uint* __restrict__ h, const int* __restrict__ gid,
            float* __restrict__ pool, float* __restrict__ cnt) {
  int wave = threadIdx.x >> 6, lane = threadIdx.x & 63;
  int start = blockIdx.x * 256 + wave * 64;
  if (start >= N_NODES) return;
  int end = min(start + 64, N_NODES);
  float ax = 0.f, ay = 0.f;
  int g = gid[start];
  int seglen = 0;
  for (int i = start; i < end; ++i) {
    int gi = gid[i];
    if (gi != g) {
      atomicAdd(&pool[g * DIM + 2 * lane], ax);
      atomicAdd(&pool[g * DIM + 2 * lane + 1], ay);
      if (lane == 0) atomicAdd(&cnt[g], (float)seglen);
      ax = ay = 0.f;
      seglen = 0;
      g = gi;
    }
    uint u = h[(size_t)i * 64 + lane];
    ax += unlo(u);
    ay += unhi(u);
    ++seglen;
  }
  atomicAdd(&pool[g * DIM + 2 * lane], ax);
  atomicAdd(&pool[g * DIM + 2 * lane + 1], ay);
  if (lane == 0) atomicAdd(&cnt[g], (float)seglen);
}

// ---------------- classifier -------------------------------------------------
__global__ void k_classifier(const float* __restrict__ pool, const float* __restrict__ cnt,
                             const float* __restrict__ Wc, const float* __restrict__ bc,
                             float* __restrict__ out) {
  int t = threadIdx.x;
  if (t >= NGRAPH * NCLS) return;
  int g = t / NCLS, c = t % NCLS;
  float inv = 1.f / fmaxf(cnt[g], 1.f);
  float s = bc[c];
  for (int k = 0; k < DIM; ++k) s += pool[g * DIM + k] * inv * Wc[k * NCLS + c];
  out[g * NCLS + c] = s;
}

// -----------------------------------------------------------------------------
extern "C" void kernel_launch(void* const* d_in, const int* in_sizes, int n_in,
                              void* d_out, int out_size, void* d_ws, size_t ws_size,
                              hipStream_t stream) {
  const float* h   = (const float*)d_in[0];
  const int* src   = (const int*)d_in[1];
  const int* dst   = (const int*)d_in[2];
  const int* gid   = (const int*)d_in[3];
  const float* W1  = (const float*)d_in[4];
  const float* b1  = (const float*)d_in[5];
  const float* W2  = (const float*)d_in[6];
  const float* b2  = (const float*)d_in[7];
  const float* Wc  = (const float*)d_in[8];
  const float* bc  = (const float*)d_in[9];
  float* out = (float*)d_out;

  size_t off = 0;
  auto alloc = [&](size_t bytes) -> char* {
    char* p = (char*)d_ws + off;
    off += (bytes + 255) & ~(size_t)255;
    return p;
  };
  ushort* hbuf    = (ushort*)alloc((size_t)(N_NODES + 1) * DIM * 2);  // +pad row
  uint*   pad1    = (uint*)(hbuf + (size_t)N_NODES * DIM);
  ushort* h1buf   = (ushort*)alloc((size_t)(N_NODES + 1) * DIM * 2);  // +pad row
  uint*   pad2    = (uint*)(h1buf + (size_t)N_NODES * DIM);
  ushort* h2buf   = (ushort*)alloc((size_t)N_NODES * DIM * 2);
  ushort* Wt1     = (ushort*)alloc(16384 * 2);
  ushort* Wt2     = (ushort*)alloc(16384 * 2);
  ushort* part    = (ushort*)alloc((size_t)2 * NBLK * RANGE * 2);     // 12.8 MB
  int*    deg_out = (int*)alloc((size_t)N_NODES * 4);
  uint*   blist   = (uint*)alloc((size_t)N_EDGES * 4);                //  6.4 MB
  int*    btot    = (int*)alloc((size_t)NBKT * 4);
  int*    bbase   = (int*)alloc((size_t)(NBKT + 1) * 4);
  int*    bcur    = (int*)alloc((size_t)NBKT * 4);
  float*  pool    = (float*)alloc((size_t)NGRAPH * DIM * 4);
  float*  cnt     = (float*)alloc((size_t)NGRAPH * 4);
  (void)ws_size; (void)in_sizes; (void)n_in; (void)out_size;

  const int NB = (N_NODES + 255) / 256;               // 391
  const size_t HIST_LDS = (RANGE / 2) * sizeof(uint); // 100 KB dynamic LDS

  k_init<<<1, 256, 0, stream>>>(pool, cnt, pad1, pad2, btot);
  // src degrees (for both prescale and layer-1 epilogue)
  k_hist<<<dim3(NBLK, 2), 256, HIST_LDS, stream>>>(src, part);
  k_degout<<<NB, 256, 0, stream>>>(part, deg_out);
  // dst bucket partition (order within bucket irrelevant)
  k_bhist<<<NBLK, 256, 0, stream>>>(dst, btot);
  k_bscan<<<1, 256, 0, stream>>>(btot, bbase, bcur);
  k_scatter<<<NBLK, 256, 0, stream>>>(src, dst, bcur, blist);
  // weights -> bf16 B^T
  k_convW<<<128, 256, 0, stream>>>(W1, W2, Wt1, Wt2);
  // layer-1 input prescale (src-side norm), fp32 -> bf16
  k_prescale<<<(N_NODES * 16 + 255) / 256, 256, 0, stream>>>((const float4*)h, deg_out,
                                                             (uint4*)hbuf);
  // layer 1: bucket aggregate + GEMM (+bias+relu+next-layer src norm)
  k_agg<<<NBKT, 512, 0, stream>>>((const uint*)hbuf, blist, bbase,
                                  Wt1, b1, deg_out, h1buf);
  // layer 2: bucket aggregate + GEMM (+bias+relu)
  k_agg<<<NBKT, 512, 0, stream>>>((const uint*)h1buf, blist, bbase,
                                  Wt2, b2, nullptr, h2buf);
  // pool + classify
  k_pool<<<(N_NODES + 255) / 256, 256, 0, stream>>>((const uint*)h2buf, gid, pool, cnt);
  k_classifier<<<1, 640, 0, stream>>>(pool, cnt, Wc, bc, out);
}

// Round 13
// 438.643 us; speedup vs baseline: 6.0104x; 6.0104x over previous
//
#include <hip/hip_runtime.h>

#define N_NODES 100000
#define N_EDGES 1600000
#define DIM     128
#define NGRAPH  64
#define NCLS    10
#define ZROW    N_NODES   // zeroed pad row id in feature buffers

#define NBLK    64                  // histogram/scatter blocks
#define EPB     (N_EDGES / NBLK)    // 25000 edges per block (exact)
#define RANGE   50000               // node ids per src-histogram pass (2 passes)
#define BNODE   64                  // nodes per dst bucket
#define NBKT    1563                // ceil(N_NODES / BNODE)

typedef __bf16 bf16x8 __attribute__((ext_vector_type(8)));
typedef float  f32x4  __attribute__((ext_vector_type(4)));

// ---- bf16 pack/unpack helpers (manual RNE) ----------------------------------
__device__ __forceinline__ ushort f2bf(float x) {
  uint b = __float_as_uint(x);
  b += 0x7fffu + ((b >> 16) & 1u);
  return (ushort)(b >> 16);
}
__device__ __forceinline__ uint pack2(float lo, float hi) {
  return (uint)f2bf(lo) | ((uint)f2bf(hi) << 16);
}
__device__ __forceinline__ float unlo(uint u) { return __uint_as_float(u << 16); }
__device__ __forceinline__ float unhi(uint u) { return __uint_as_float(u & 0xffff0000u); }

__device__ __forceinline__ void acc8(float* a, uint4 u) {
  a[0] += unlo(u.x); a[1] += unhi(u.x);
  a[2] += unlo(u.y); a[3] += unhi(u.y);
  a[4] += unlo(u.z); a[5] += unhi(u.z);
  a[6] += unlo(u.w); a[7] += unhi(u.w);
}

// ---------------- init: zero pool, cnt, pad rows, bucket totals --------------
__global__ void k_init(float* __restrict__ pool, float* __restrict__ cnt,
                       uint* __restrict__ pad1, uint* __restrict__ pad2,
                       int* __restrict__ btot) {
  int t = threadIdx.x;
  for (int i = t; i < NGRAPH * DIM; i += 256) pool[i] = 0.f;
  if (t < NGRAPH) cnt[t] = 0.f;
  if (t < DIM / 2) { pad1[t] = 0u; pad2[t] = 0u; }
  for (int i = t; i < NBKT; i += 256) btot[i] = 0;
}

// ---------------- src-degree histograms (2 ranges, LDS-privatized) -----------
__global__ __launch_bounds__(256)
void k_hist(const int* __restrict__ src, ushort* __restrict__ part) {
  extern __shared__ uint cnt_[];   // RANGE/2 words = 100 KB
  int p = blockIdx.y;              // src range 0/1
  int b = blockIdx.x;
  int base = p * RANGE;
  for (int i = threadIdx.x; i < RANGE / 2; i += 256) cnt_[i] = 0;
  __syncthreads();
  int cb = b * EPB;
  for (int j = threadIdx.x; j < EPB; j += 256) {
    int v = src[cb + j] - base;
    if ((unsigned)v < RANGE) atomicAdd(&cnt_[v >> 1], 1u << ((v & 1) * 16));
  }
  __syncthreads();
  uint* o = (uint*)(part + ((size_t)p * NBLK + b) * RANGE);
  for (int i = threadIdx.x; i < RANGE / 2; i += 256) o[i] = cnt_[i];
}

// ---------------- sum partials -> deg_out ------------------------------------
__global__ void k_degout(const ushort* __restrict__ part, int* __restrict__ deg_out) {
  int n = blockIdx.x * 256 + threadIdx.x;
  if (n >= N_NODES) return;
  int r = n / RANGE, i = n % RANGE;
  const ushort* p0 = part + ((size_t)r * NBLK) * RANGE + i;
  int s = 0;
  for (int b = 0; b < NBLK; ++b) s += p0[(size_t)b * RANGE];
  deg_out[n] = s;
}

// ---------------- dst bucket histogram ---------------------------------------
__global__ __launch_bounds__(256)
void k_bhist(const int* __restrict__ dst, int* __restrict__ btot) {
  __shared__ uint h[NBKT];
  for (int i = threadIdx.x; i < NBKT; i += 256) h[i] = 0;
  __syncthreads();
  int cb = blockIdx.x * EPB;
  for (int j = threadIdx.x; j < EPB; j += 256)
    atomicAdd(&h[dst[cb + j] >> 6], 1u);
  __syncthreads();
  for (int i = threadIdx.x; i < NBKT; i += 256)
    if (h[i]) atomicAdd(&btot[i], (int)h[i]);
}

// ---------------- bucket scan: btot -> bbase (exclusive) + cursor ------------
__global__ void k_bscan(const int* __restrict__ btot, int* __restrict__ bbase,
                        int* __restrict__ bcur) {
  __shared__ int tot[256];
  int t = threadIdx.x;     // 256 threads x 7 buckets each (1792 >= 1564)
  int c[7]; int s = 0;
  #pragma unroll
  for (int i = 0; i < 7; ++i) {
    int gi = t * 7 + i;
    c[i] = (gi < NBKT) ? btot[gi] : 0;
    s += c[i];
  }
  tot[t] = s;
  __syncthreads();
  for (int off = 1; off < 256; off <<= 1) {
    int x = (t >= off) ? tot[t - off] : 0;
    __syncthreads();
    tot[t] += x;
    __syncthreads();
  }
  int run = tot[t] - s;    // exclusive offset of this thread's chunk
  #pragma unroll
  for (int i = 0; i < 7; ++i) {
    int gi = t * 7 + i;
    if (gi <= NBKT) {
      bbase[gi] = run;
      if (gi < NBKT) bcur[gi] = run;
    }
    run += c[i];
  }
}

// ---------------- scatter edges into dst buckets (unordered within bucket) ---
__global__ __launch_bounds__(256)
void k_scatter(const int* __restrict__ src, const int* __restrict__ dst,
               int* __restrict__ bcur, uint* __restrict__ blist) {
  __shared__ uint h[NBKT];
  __shared__ uint st[NBKT];
  for (int i = threadIdx.x; i < NBKT; i += 256) h[i] = 0;
  __syncthreads();
  int cb = blockIdx.x * EPB;
  for (int j = threadIdx.x; j < EPB; j += 256)
    atomicAdd(&h[dst[cb + j] >> 6], 1u);
  __syncthreads();
  for (int i = threadIdx.x; i < NBKT; i += 256) {
    st[i] = (uint)atomicAdd(&bcur[i], (int)h[i]);
    h[i] = 0;   // reuse as local cursor
  }
  __syncthreads();
  for (int j = threadIdx.x; j < EPB; j += 256) {
    int d = dst[cb + j];
    int s = src[cb + j];
    int bk = d >> 6;
    uint pos = st[bk] + atomicAdd(&h[bk], 1u);
    blist[pos] = (uint)s | ((uint)(d & 63) << 17);   // src<2^17, dl 6 bits
  }
}

// ---------------- per-bucket counting sort -> CSR (int LDS atomics only) -----
// One block per bucket: 64-bin histogram, wave-shfl exclusive scan, scatter
// into csr_src; writes row_ptr for the bucket's 64 nodes.
__global__ __launch_bounds__(256)
void k_bsort(const uint* __restrict__ blist, const int* __restrict__ bbase,
             int* __restrict__ csr_src, int* __restrict__ row_ptr) {
  __shared__ uint lcnt[BNODE];
  __shared__ uint pref[BNODE];
  __shared__ uint cur[BNODE];
  int bk = blockIdx.x, t = threadIdx.x;
  if (t < BNODE) lcnt[t] = 0;
  __syncthreads();
  int beg = bbase[bk], end = bbase[bk + 1];
  for (int j = beg + t; j < end; j += 256)
    atomicAdd(&lcnt[blist[j] >> 17], 1u);
  __syncthreads();
  if (t < BNODE) {   // wave 0: inclusive shfl scan of 64 -> exclusive prefix
    uint v = lcnt[t];
    uint inc = v;
    #pragma unroll
    for (int off = 1; off < 64; off <<= 1) {
      uint x = __shfl_up(inc, off);
      if (t >= off) inc += x;
    }
    pref[t] = inc - v;
    cur[t] = inc - v;
    int n = (bk << 6) + t;
    if (n <= N_NODES) row_ptr[n] = beg + (int)(inc - v);
  }
  __syncthreads();
  for (int j = beg + t; j < end; j += 256) {
    uint e = blist[j];
    uint old = atomicAdd(&cur[e >> 17], 1u);
    csr_src[beg + (int)old] = (int)(e & 0x1FFFFu);
  }
}

// ---------------- W -> bf16 transposed (B^T layout: Wt[c][k]) ----------------
__global__ void k_convW(const float* __restrict__ W1, const float* __restrict__ W2,
                        ushort* __restrict__ Wt1, ushort* __restrict__ Wt2) {
  int idx = blockIdx.x * 256 + threadIdx.x;
  const float* W = (idx < 16384) ? W1 : W2;
  ushort* Wt = (idx < 16384) ? Wt1 : Wt2;
  int t = idx & 16383;
  int c = t >> 7, k = t & 127;
  Wt[c * 128 + k] = f2bf(W[k * 128 + c]);
}

// ---------------- prescale: hs = bf16(h * rsqrt(deg_out[row])) ---------------
__global__ void k_prescale(const float4* __restrict__ h4, const int* __restrict__ deg_out,
                           uint4* __restrict__ out4) {
  int idx = blockIdx.x * blockDim.x + threadIdx.x;
  if (idx < N_NODES * 16) {
    int row = idx >> 4;
    int d = deg_out[row];
    float s = d > 0 ? rsqrtf((float)d) : 0.f;
    float4 v0 = h4[idx * 2];
    float4 v1 = h4[idx * 2 + 1];
    uint4 o;
    o.x = pack2(v0.x * s, v0.y * s);
    o.y = pack2(v0.z * s, v0.w * s);
    o.z = pack2(v1.x * s, v1.y * s);
    o.w = pack2(v1.z * s, v1.w * s);
    out4[idx] = o;
  }
}

// ---------------- fused gather + MFMA GEMM (group-per-node, PROVEN R5) -------
__global__ __launch_bounds__(256)
void k_gg(const uint* __restrict__ hs, const int* __restrict__ row_ptr,
          const int* __restrict__ csr_src, const ushort* __restrict__ Wt,
          const float* __restrict__ bias, const int* __restrict__ deg_scale,
          ushort* __restrict__ out) {
  __shared__ ushort As[16][136];
  int wv = threadIdx.x >> 6, lane = threadIdx.x & 63;
  int strip = blockIdx.x;
  int g = lane >> 4;      // group = node slot within wave
  int li = lane & 15;     // 16B column segment slot
  int glane = g * 16;

  int n = strip * 16 + wv * 4 + g;
  int beg = row_ptr[n];
  int deg = row_ptr[n + 1] - beg;

  float a[8] = {};

  int nxt = (li < deg) ? csr_src[beg + li] : ZROW;
  for (int cb = 0; cb < deg; cb += 16) {
    int idx = nxt;
    int rem = deg - cb - 16;
    if (rem > 0) nxt = (li < rem) ? csr_src[beg + cb + 16 + li] : ZROW;
    #pragma unroll
    for (int e = 0; e < 16; e += 4) {
      int s0 = __shfl(idx, glane + e);
      int s1 = __shfl(idx, glane + e + 1);
      int s2 = __shfl(idx, glane + e + 2);
      int s3 = __shfl(idx, glane + e + 3);
      uint4 u0 = *(const uint4*)(hs + (size_t)s0 * 64 + li * 4);
      uint4 u1 = *(const uint4*)(hs + (size_t)s1 * 64 + li * 4);
      uint4 u2 = *(const uint4*)(hs + (size_t)s2 * 64 + li * 4);
      uint4 u3 = *(const uint4*)(hs + (size_t)s3 * 64 + li * 4);
      acc8(a, u0); acc8(a, u1); acc8(a, u2); acc8(a, u3);
    }
  }

  {
    float sc = deg > 0 ? rsqrtf((float)deg) : 0.f;
    uint4 o;
    o.x = pack2(a[0] * sc, a[1] * sc);
    o.y = pack2(a[2] * sc, a[3] * sc);
    o.z = pack2(a[4] * sc, a[5] * sc);
    o.w = pack2(a[6] * sc, a[7] * sc);
    *(uint4*)&As[wv * 4 + g][li * 8] = o;
  }

  int lr = lane & 15, lk = lane >> 4;
  bf16x8 bfrag[4][2];
  #pragma unroll
  for (int ks = 0; ks < 4; ++ks)
    #pragma unroll
    for (int c2 = 0; c2 < 2; ++c2)
      bfrag[ks][c2] = *(const bf16x8*)(Wt + (size_t)((wv * 2 + c2) * 16 + lr) * 128 +
                                       ks * 32 + lk * 8);
  __syncthreads();

  f32x4 acc[2] = {};
  #pragma unroll
  for (int ks = 0; ks < 4; ++ks) {
    bf16x8 af = *(const bf16x8*)&As[lr][ks * 32 + lk * 8];
    acc[0] = __builtin_amdgcn_mfma_f32_16x16x32_bf16(af, bfrag[ks][0], acc[0], 0, 0, 0);
    acc[1] = __builtin_amdgcn_mfma_f32_16x16x32_bf16(af, bfrag[ks][1], acc[1], 0, 0, 0);
  }

  #pragma unroll
  for (int rr = 0; rr < 4; ++rr) {
    int row = strip * 16 + lk * 4 + rr;
    float s = 1.f;
    if (deg_scale) {
      int d = deg_scale[row];
      s = d > 0 ? rsqrtf((float)d) : 0.f;
    }
    #pragma unroll
    for (int c2 = 0; c2 < 2; ++c2) {
      int col = (wv * 2 + c2) * 16 + lr;
      float v = fmaxf(acc[c2][rr] + bias[col], 0.f) * s;
      out[(size_t)row * 128 + col] = f2bf(v);
    }
  }
}

// ---------------- segmented mean-pool: 64 rows per wave ----------------------
__global__ __launch_bounds__(256)
void k_pool(const uint* __restrict__ h, const int* __restrict__ gid,
            float* __restrict__ pool, float* __restrict__ cnt) {
  int wave = threadIdx.x >> 6, lane = threadIdx.x & 63;
  int start = blockIdx.x * 256 + wave * 64;
  if (start >= N_NODES) return;
  int end = min(start + 64, N_NODES);
  float ax = 0.f, ay = 0.f;
  int g = gid[start];
  int seglen = 0;
  for (int i = start; i < end; ++i) {
    int gi = gid[i];
    if (gi != g) {
      atomicAdd(&pool[g * DIM + 2 * lane], ax);
      atomicAdd(&pool[g * DIM + 2 * lane + 1], ay);
      if (lane == 0) atomicAdd(&cnt[g], (float)seglen);
      ax = ay = 0.f;
      seglen = 0;
      g = gi;
    }
    uint u = h[(size_t)i * 64 + lane];
    ax += unlo(u);
    ay += unhi(u);
    ++seglen;
  }
  atomicAdd(&pool[g * DIM + 2 * lane], ax);
  atomicAdd(&pool[g * DIM + 2 * lane + 1], ay);
  if (lane == 0) atomicAdd(&cnt[g], (float)seglen);
}

// ---------------- classifier: 64 blocks x 128 thr, shfl+LDS reduce -----------
__global__ void k_classifier(const float* __restrict__ pool, const float* __restrict__ cnt,
                             const float* __restrict__ Wc, const float* __restrict__ bc,
                             float* __restrict__ out) {
  __shared__ float red[2][NCLS];
  int g = blockIdx.x, t = threadIdx.x;
  float inv = 1.f / fmaxf(cnt[g], 1.f);
  float v = pool[g * DIM + t] * inv;
  float p[NCLS];
  #pragma unroll
  for (int c = 0; c < NCLS; ++c) p[c] = v * Wc[t * NCLS + c];
  #pragma unroll
  for (int c = 0; c < NCLS; ++c) {
    float x = p[c];
    #pragma unroll
    for (int off = 32; off > 0; off >>= 1) x += __shfl_down(x, off);
    if ((t & 63) == 0) red[t >> 6][c] = x;
  }
  __syncthreads();
  if (t < NCLS) out[g * NCLS + t] = red[0][t] + red[1][t] + bc[t];
}

// -----------------------------------------------------------------------------
extern "C" void kernel_launch(void* const* d_in, const int* in_sizes, int n_in,
                              void* d_out, int out_size, void* d_ws, size_t ws_size,
                              hipStream_t stream) {
  const float* h   = (const float*)d_in[0];
  const int* src   = (const int*)d_in[1];
  const int* dst   = (const int*)d_in[2];
  const int* gid   = (const int*)d_in[3];
  const float* W1  = (const float*)d_in[4];
  const float* b1  = (const float*)d_in[5];
  const float* W2  = (const float*)d_in[6];
  const float* b2  = (const float*)d_in[7];
  const float* Wc  = (const float*)d_in[8];
  const float* bc  = (const float*)d_in[9];
  float* out = (float*)d_out;

  size_t off = 0;
  auto alloc = [&](size_t bytes) -> char* {
    char* p = (char*)d_ws + off;
    off += (bytes + 255) & ~(size_t)255;
    return p;
  };
  ushort* hbuf    = (ushort*)alloc((size_t)(N_NODES + 1) * DIM * 2);  // +pad row
  uint*   pad1    = (uint*)(hbuf + (size_t)N_NODES * DIM);
  ushort* h1buf   = (ushort*)alloc((size_t)(N_NODES + 1) * DIM * 2);  // +pad row
  uint*   pad2    = (uint*)(h1buf + (size_t)N_NODES * DIM);
  ushort* h2buf   = (ushort*)alloc((size_t)N_NODES * DIM * 2);
  ushort* Wt1     = (ushort*)alloc(16384 * 2);
  ushort* Wt2     = (ushort*)alloc(16384 * 2);
  ushort* part    = (ushort*)alloc((size_t)2 * NBLK * RANGE * 2);     // 12.8 MB
  int*    deg_out = (int*)alloc((size_t)N_NODES * 4);
  uint*   blist   = (uint*)alloc((size_t)N_EDGES * 4);                //  6.4 MB
  int*    csr_src = (int*)alloc((size_t)N_EDGES * 4);                 //  6.4 MB
  int*    row_ptr = (int*)alloc((size_t)(N_NODES + 1) * 4);
  int*    btot    = (int*)alloc((size_t)NBKT * 4);
  int*    bbase   = (int*)alloc((size_t)(NBKT + 1) * 4);
  int*    bcur    = (int*)alloc((size_t)NBKT * 4);
  float*  pool    = (float*)alloc((size_t)NGRAPH * DIM * 4);
  float*  cnt     = (float*)alloc((size_t)NGRAPH * 4);
  (void)ws_size; (void)in_sizes; (void)n_in; (void)out_size;

  const int NB = (N_NODES + 255) / 256;               // 391
  const size_t HIST_LDS = (RANGE / 2) * sizeof(uint); // 100 KB dynamic LDS

  k_init<<<1, 256, 0, stream>>>(pool, cnt, pad1, pad2, btot);
  // src degrees (for prescale + layer-1 epilogue)
  k_hist<<<dim3(NBLK, 2), 256, HIST_LDS, stream>>>(src, part);
  k_degout<<<NB, 256, 0, stream>>>(part, deg_out);
  // dst bucket partition + per-bucket counting sort -> CSR
  k_bhist<<<NBLK, 256, 0, stream>>>(dst, btot);
  k_bscan<<<1, 256, 0, stream>>>(btot, bbase, bcur);
  k_scatter<<<NBLK, 256, 0, stream>>>(src, dst, bcur, blist);
  k_bsort<<<NBKT, 256, 0, stream>>>(blist, bbase, csr_src, row_ptr);
  // weights -> bf16 B^T
  k_convW<<<128, 256, 0, stream>>>(W1, W2, Wt1, Wt2);
  // layer-1 input prescale (src-side norm), fp32 -> bf16
  k_prescale<<<(N_NODES * 16 + 255) / 256, 256, 0, stream>>>((const float4*)h, deg_out,
                                                             (uint4*)hbuf);
  // layer 1: fused gather + GEMM (+bias+relu+next-layer src norm)
  k_gg<<<N_NODES / 16, 256, 0, stream>>>((const uint*)hbuf, row_ptr, csr_src,
                                         Wt1, b1, deg_out, h1buf);
  // layer 2: fused gather + GEMM (+bias+relu)
  k_gg<<<N_NODES / 16, 256, 0, stream>>>((const uint*)h1buf, row_ptr, csr_src,
                                         Wt2, b2, nullptr, h2buf);
  // pool + classify
  k_pool<<<(N_NODES + 255) / 256, 256, 0, stream>>>((const uint*)h2buf, gid, pool, cnt);
  k_classifier<<<NGRAPH, 128, 0, stream>>>(pool, cnt, Wc, bc, out);
}